// Round 4
// baseline (832.718 us; speedup 1.0000x reference)
//
#include <hip/hip_runtime.h>

#define SL    48   // sequence length
#define OBS   64   // observation dim
#define HID   84   // hidden dim
#define BATCH 32
#define PTOL  1e-3f  // tol on max|dW|,|dK| between consecutive Riccati steps

// LDS layout (floats); every OFF*4 is 16B-aligned.
#define OFF_P   0        // 84 x 96 (swizzled chunks)
#define OFF_T2  8064     // 64 x 96  [aliased by U]
#define OFF_T   14208    // 84 x 64
#define OFF_U   8064     // 84 x 96 (alias of T2/T region; disjoint lifetime)
#define OFF_S   19584    // 64 x 64
#define OFF_K   23680    // 84 x 64
#define OFF_RB  29056    // 8 x 64 GJ pivot row panel
#define OFF_CB  29568    // 64 x 8 GJ pivot col panel
#define OFF_RED 30080    // 8
#define SMEM_F  30088
#define SMEM_BYTES (SMEM_F * 4)

__device__ __forceinline__ int swz(int row, int c) { return c ^ ((row >> 2) & 7); }

// NT-GEMM 4x4 tile: acc[r][s] += sum_k X[i0+r][k] * Y[j0+s][k], k = 4*KC.
template<int KC, int XS, bool XSW, int YS, bool YSW>
__device__ __forceinline__ void tile_nt(const float* __restrict__ X,
                                        const float* __restrict__ Y,
                                        int i0, int j0, float acc[4][4])
{
    const int xk = XSW ? ((i0 >> 2) & 7) : 0;
    const int yk = YSW ? ((j0 >> 2) & 7) : 0;
    #pragma unroll 4
    for (int c = 0; c < KC; ++c) {
        const int xc = (XSW ? (c ^ xk) : c) << 2;
        const int yc = (YSW ? (c ^ yk) : c) << 2;
        float4 a[4], b[4];
        #pragma unroll
        for (int r = 0; r < 4; ++r)
            a[r] = *reinterpret_cast<const float4*>(&X[(i0 + r) * XS + xc]);
        #pragma unroll
        for (int s = 0; s < 4; ++s)
            b[s] = *reinterpret_cast<const float4*>(&Y[(j0 + s) * YS + yc]);
        #pragma unroll
        for (int r = 0; r < 4; ++r)
            #pragma unroll
            for (int s = 0; s < 4; ++s)
                acc[r][s] += a[r].x * b[s].x + a[r].y * b[s].y
                           + a[r].z * b[s].z + a[r].w * b[s].w;
    }
}

__device__ __forceinline__ void inv4_inplace(float a[4][4])
{
    float o[4][4] = {{1,0,0,0},{0,1,0,0},{0,0,1,0},{0,0,0,1}};
    #pragma unroll
    for (int p = 0; p < 4; ++p) {
        const float f = 1.0f / a[p][p];
        #pragma unroll
        for (int c = 0; c < 4; ++c) { a[p][c] *= f; o[p][c] *= f; }
        #pragma unroll
        for (int r = 0; r < 4; ++r) {
            if (r == p) continue;
            const float g = a[r][p];
            #pragma unroll
            for (int c = 0; c < 4; ++c) { a[r][c] -= g * a[p][c]; o[r][c] -= g * o[p][c]; }
        }
    }
    #pragma unroll
    for (int r = 0; r < 4; ++r)
        #pragma unroll
        for (int c = 0; c < 4; ++c) a[r][c] = o[r][c];
}

// ---------------------------------------------------------------------------
// Phase 1: Riccati sweep. Single block, 512 threads, all-LDS working set.
// Emits per step: K^T (for prep+convergence) and W = S^{-1}.
// ---------------------------------------------------------------------------
__global__ __launch_bounds__(512)
void riccati_kernel(const float* __restrict__ Ag,   // HID x HID
                    const float* __restrict__ Cg,   // OBS x HID
                    float* __restrict__ Ktg,        // SL * OBS * HID
                    float* __restrict__ Wg,         // SL * OBS * OBS
                    int*   __restrict__ ncvp)
{
    extern __shared__ float smem[];
    float*  sP   = smem + OFF_P;
    float*  sT2  = smem + OFF_T2;
    float*  sT   = smem + OFF_T;
    float*  sU   = smem + OFF_U;
    float*  sS   = smem + OFF_S;
    float*  sK   = smem + OFF_K;
    float*  rbuf = smem + OFF_RB;
    float*  cbuf = smem + OFF_CB;
    float*  sRed = smem + OFF_RED;
    float4* sP4  = reinterpret_cast<float4*>(sP);
    float4* sT24 = reinterpret_cast<float4*>(sT2);
    float4* sT4  = reinterpret_cast<float4*>(sT);
    float4* sU4  = reinterpret_cast<float4*>(sU);
    float4* sS4  = reinterpret_cast<float4*>(sS);
    float4* sK4  = reinterpret_cast<float4*>(sK);

    const int t = threadIdx.x;

    // P = I
    for (int u = t; u < HID * 24; u += 512) {
        const int row = u / 24, pc = u % 24;
        const int lc = pc ^ ((row >> 2) & 7);
        float4 v = make_float4(0.f, 0.f, 0.f, 0.f);
        if (lc < 21) {
            const int base = lc * 4;
            if (row == base)     v.x = 1.f;
            if (row == base + 1) v.y = 1.f;
            if (row == base + 2) v.z = 1.f;
            if (row == base + 3) v.w = 1.f;
        }
        sP4[row * 24 + pc] = v;
    }
    __syncthreads();

    int ncv = SL;
    for (int step = 0; step < SL; ++step) {
        // ---- P1: T2 = C * P ; T = T2^T
        if (t < 336) {
            const int a0 = (t / 21) * 4, i0 = (t % 21) * 4;
            float acc[4][4] = {};
            tile_nt<21, HID, false, 96, true>(Cg, sP, a0, i0, acc);
            #pragma unroll
            for (int r = 0; r < 4; ++r)
                sT24[(a0 + r) * 24 + swz(a0 + r, i0 >> 2)] =
                    make_float4(acc[r][0], acc[r][1], acc[r][2], acc[r][3]);
            #pragma unroll
            for (int s = 0; s < 4; ++s)
                sT4[(i0 + s) * 16 + swz(i0 + s, a0 >> 2)] =
                    make_float4(acc[0][s], acc[1][s], acc[2][s], acc[3][s]);
        }
        __syncthreads();

        // ---- P2: S = T2 * C^T
        if (t < 256) {
            const int a0 = (t / 16) * 4, b0 = (t % 16) * 4;
            float acc[4][4] = {};
            tile_nt<21, 96, true, HID, false>(sT2, Cg, a0, b0, acc);
            #pragma unroll
            for (int r = 0; r < 4; ++r)
                sS4[(a0 + r) * 16 + swz(a0 + r, b0 >> 2)] =
                    make_float4(acc[r][0], acc[r][1], acc[r][2], acc[r][3]);
        }
        __syncthreads();

        // ---- P3: block-8 Gauss-Jordan inverse of S (SPD)
        for (int g = 0; g < 8; ++g) {
            const int p0 = g * 8;
            // snapshot pivot row-panel (8x64) and col-panel (64x8), logical layout
            if (t < 128) {
                const int r = t >> 4, c = t & 15;
                reinterpret_cast<float4*>(rbuf)[r * 16 + c] =
                    sS4[(p0 + r) * 16 + swz(p0 + r, c)];
            } else if (t < 256) {
                const int u = t - 128, i = u >> 1, h = u & 1;
                reinterpret_cast<float4*>(cbuf)[i * 2 + h] =
                    sS4[i * 16 + swz(i, 2 * g + h)];
            }
            __syncthreads();
            // replicated 8x8 pivot inverse via Schur of 4x4 blocks
            float pinv[8][8];
            {
                float Ai[4][4], F[4][4], E[4][4], Sc[4][4], G[4][4];
                #pragma unroll
                for (int r = 0; r < 4; ++r)
                    #pragma unroll
                    for (int c = 0; c < 4; ++c) Ai[r][c] = rbuf[r * 64 + p0 + c];
                inv4_inplace(Ai);
                #pragma unroll
                for (int r = 0; r < 4; ++r)
                    #pragma unroll
                    for (int c = 0; c < 4; ++c) {
                        float s = 0.f;
                        #pragma unroll
                        for (int m = 0; m < 4; ++m) s += Ai[r][m] * rbuf[m * 64 + p0 + 4 + c];
                        F[r][c] = s;   // Ai*B
                    }
                #pragma unroll
                for (int r = 0; r < 4; ++r)
                    #pragma unroll
                    for (int c = 0; c < 4; ++c) {
                        float s = rbuf[(4 + r) * 64 + p0 + 4 + c];   // D
                        #pragma unroll
                        for (int m = 0; m < 4; ++m) s -= rbuf[(4 + r) * 64 + p0 + m] * F[m][c];
                        Sc[r][c] = s;  // D - C*F
                    }
                inv4_inplace(Sc);      // Sci
                #pragma unroll
                for (int r = 0; r < 4; ++r)
                    #pragma unroll
                    for (int c = 0; c < 4; ++c) {
                        float s = 0.f;
                        #pragma unroll
                        for (int m = 0; m < 4; ++m) s += rbuf[(4 + r) * 64 + p0 + m] * Ai[m][c];
                        E[r][c] = s;   // C*Ai
                    }
                #pragma unroll
                for (int r = 0; r < 4; ++r)
                    #pragma unroll
                    for (int c = 0; c < 4; ++c) {
                        float s = 0.f;
                        #pragma unroll
                        for (int m = 0; m < 4; ++m) s += Sc[r][m] * E[m][c];
                        G[r][c] = s;   // Sci*E
                    }
                #pragma unroll
                for (int r = 0; r < 4; ++r)
                    #pragma unroll
                    for (int c = 0; c < 4; ++c) {
                        float tr = 0.f, tl = 0.f;
                        #pragma unroll
                        for (int m = 0; m < 4; ++m) { tr += F[r][m] * Sc[m][c]; tl += F[r][m] * G[m][c]; }
                        pinv[r][4 + c] = -tr;              // -F*Sci
                        pinv[r][c]     = Ai[r][c] + tl;    // Ai + F*Sci*E
                        pinv[4 + r][c]     = -G[r][c];     // -Sci*E
                        pinv[4 + r][4 + c] = Sc[r][c];     // Sci
                    }
            }
            // update: thread owns (i, c0) and (i, c0+8) -> same row i, e8 shared
            const int i = t >> 3, c0 = t & 7;
            const bool piv = (i >= p0) && (i < p0 + 8);
            float e8[8];
            if (!piv) {
                #pragma unroll
                for (int l = 0; l < 8; ++l) {
                    float s = 0.f;
                    #pragma unroll
                    for (int m = 0; m < 8; ++m) s += cbuf[i * 8 + m] * pinv[m][l];
                    e8[l] = s;
                }
            }
            #pragma unroll
            for (int rep = 0; rep < 2; ++rep) {
                const int c = c0 + rep * 8;
                float o[4];
                if (piv) {
                    const int r = i - p0;
                    if (c == 2 * g) {
                        o[0] = pinv[r][0]; o[1] = pinv[r][1]; o[2] = pinv[r][2]; o[3] = pinv[r][3];
                    } else if (c == 2 * g + 1) {
                        o[0] = pinv[r][4]; o[1] = pinv[r][5]; o[2] = pinv[r][6]; o[3] = pinv[r][7];
                    } else {
                        #pragma unroll
                        for (int jj = 0; jj < 4; ++jj) {
                            float s = 0.f;
                            #pragma unroll
                            for (int l = 0; l < 8; ++l) s += pinv[r][l] * rbuf[l * 64 + 4 * c + jj];
                            o[jj] = s;
                        }
                    }
                } else {
                    if (c == 2 * g) {
                        o[0] = -e8[0]; o[1] = -e8[1]; o[2] = -e8[2]; o[3] = -e8[3];
                    } else if (c == 2 * g + 1) {
                        o[0] = -e8[4]; o[1] = -e8[5]; o[2] = -e8[6]; o[3] = -e8[7];
                    } else {
                        const float4 old = sS4[i * 16 + swz(i, c)];
                        o[0] = old.x; o[1] = old.y; o[2] = old.z; o[3] = old.w;
                        #pragma unroll
                        for (int l = 0; l < 8; ++l) {
                            const float el = e8[l];
                            #pragma unroll
                            for (int jj = 0; jj < 4; ++jj) o[jj] -= el * rbuf[l * 64 + 4 * c + jj];
                        }
                    }
                }
                sS4[i * 16 + swz(i, c)] = make_float4(o[0], o[1], o[2], o[3]);
            }
            __syncthreads();
        }

        // ---- P4: K = T*W -> sK + Ktg; stream W; convergence on dK,dW
        float maxd = 0.0f;
        float* Ktstep = Ktg + step * OBS * HID;
        const float* Ktprev = Ktg + (step - 1) * OBS * HID;
        if (t < 336) {
            const int i0 = (t / 16) * 4, j0 = (t % 16) * 4;
            float acc[4][4] = {};
            tile_nt<16, 64, true, 64, true>(sT, sS, i0, j0, acc);
            #pragma unroll
            for (int r = 0; r < 4; ++r)
                sK4[(i0 + r) * 16 + swz(i0 + r, j0 >> 2)] =
                    make_float4(acc[r][0], acc[r][1], acc[r][2], acc[r][3]);
            #pragma unroll
            for (int s = 0; s < 4; ++s) {
                const float4 nv = make_float4(acc[0][s], acc[1][s], acc[2][s], acc[3][s]);
                if (step > 0) {
                    const float4 ov =
                        *reinterpret_cast<const float4*>(&Ktprev[(j0 + s) * HID + i0]);
                    maxd = fmaxf(maxd, fmaxf(fmaxf(fabsf(nv.x - ov.x), fabsf(nv.y - ov.y)),
                                             fmaxf(fabsf(nv.z - ov.z), fabsf(nv.w - ov.w))));
                }
                *reinterpret_cast<float4*>(&Ktstep[(j0 + s) * HID + i0]) = nv;
            }
        }
        {
            float* Wstep = Wg + step * OBS * OBS;
            const float* Wprev = Wg + (step - 1) * OBS * OBS;
            #pragma unroll
            for (int rep = 0; rep < 2; ++rep) {
                const int u = t + rep * 512;
                const int row = u >> 4, c = u & 15;
                const float4 nv = sS4[row * 16 + swz(row, c)];
                if (step > 0) {
                    const float4 ov = reinterpret_cast<const float4*>(Wprev)[row * 16 + c];
                    maxd = fmaxf(maxd, fmaxf(fmaxf(fabsf(nv.x - ov.x), fabsf(nv.y - ov.y)),
                                             fmaxf(fabsf(nv.z - ov.z), fabsf(nv.w - ov.w))));
                }
                reinterpret_cast<float4*>(Wstep)[row * 16 + c] = nv;
            }
        }
        #pragma unroll
        for (int mo = 32; mo >= 1; mo >>= 1)
            maxd = fmaxf(maxd, __shfl_xor(maxd, mo));
        if ((t & 63) == 0) sRed[t >> 6] = maxd;
        __syncthreads();
        float mm = sRed[0];
        #pragma unroll
        for (int w = 1; w < 8; ++w) mm = fmaxf(mm, sRed[w]);
        if (step > 0 && mm < PTOL) { ncv = step + 1; break; }
        if (step == SL - 1) break;

        // ---- P5: PF = P - K*T^T (in place)
        if (t < 441) {
            const int i0 = (t / 21) * 4, j0 = (t % 21) * 4;
            float acc[4][4] = {};
            tile_nt<16, 64, true, 64, true>(sK, sT, i0, j0, acc);
            #pragma unroll
            for (int r = 0; r < 4; ++r) {
                float4* p = &sP4[(i0 + r) * 24 + swz(i0 + r, j0 >> 2)];
                float4 v = *p;
                v.x -= acc[r][0]; v.y -= acc[r][1]; v.z -= acc[r][2]; v.w -= acc[r][3];
                *p = v;
            }
        }
        __syncthreads();

        // ---- P6: U = A * PF (PF symmetric)
        if (t < 441) {
            const int i0 = (t / 21) * 4, j0 = (t % 21) * 4;
            float acc[4][4] = {};
            tile_nt<21, HID, false, 96, true>(Ag, sP, i0, j0, acc);
            #pragma unroll
            for (int r = 0; r < 4; ++r)
                sU4[(i0 + r) * 24 + swz(i0 + r, j0 >> 2)] =
                    make_float4(acc[r][0], acc[r][1], acc[r][2], acc[r][3]);
        }
        __syncthreads();

        // ---- P7: P = A * U^T + I
        if (t < 441) {
            const int i0 = (t / 21) * 4, j0 = (t % 21) * 4;
            float acc[4][4] = {};
            tile_nt<21, HID, false, 96, true>(Ag, sU, i0, j0, acc);
            #pragma unroll
            for (int r = 0; r < 4; ++r) {
                float4 v = make_float4(acc[r][0], acc[r][1], acc[r][2], acc[r][3]);
                if (i0 + r == j0 + 0) v.x += 1.f;
                if (i0 + r == j0 + 1) v.y += 1.f;
                if (i0 + r == j0 + 2) v.z += 1.f;
                if (i0 + r == j0 + 3) v.w += 1.f;
                sP4[(i0 + r) * 24 + swz(i0 + r, j0 >> 2)] = v;
            }
        }
        __syncthreads();
    }

    if (t == 0) *ncvp = ncv;
}

// ---------------------------------------------------------------------------
// Phase 1b: AK_s = A * K_s for s < ncv, stored transposed (OBS x HID).
// ---------------------------------------------------------------------------
__global__ __launch_bounds__(256)
void prep_kernel(const float* __restrict__ Ag,
                 const float* __restrict__ Ktg,
                 const int*   __restrict__ ncvp,
                 float* __restrict__ AKtg)
{
    const int s = blockIdx.x;
    if (s >= *ncvp) return;
    const float* Kts  = Ktg  + s * OBS * HID;
    float*       AKts = AKtg + s * OBS * HID;
    for (int u = threadIdx.x; u < 336; u += 256) {
        const int i0 = (u / 16) * 4, j0 = (u % 16) * 4;
        float acc[4][4] = {};
        // AK[i][j] = sum_k A[i][k] * K[k][j]; Kt row j holds K[.][j]
        tile_nt<21, HID, false, HID, false>(Ag, Kts, i0, j0, acc);
        #pragma unroll
        for (int c = 0; c < 4; ++c)
            *reinterpret_cast<float4*>(&AKts[(j0 + c) * HID + i0]) =
                make_float4(acc[0][c], acc[1][c], acc[2][c], acc[3][c]);
    }
}

// ---------------------------------------------------------------------------
// Phase 2: per-batch Kalman sweep, single wave per block (no real barriers).
// x' = A x + AK e;  q += e^T W e.
// ---------------------------------------------------------------------------
__global__ __launch_bounds__(64)
void sweep_kernel(const float* __restrict__ Y,     // BATCH x (SL*OBS)
                  const float* __restrict__ Ag,
                  const float* __restrict__ Cg,
                  const float* __restrict__ AKtg,  // SL * OBS * HID
                  const float* __restrict__ Wg,    // SL * OBS * OBS
                  const int*   __restrict__ ncvp,
                  float* __restrict__ partials)
{
    __shared__ float sCt[HID * OBS];  // sCt[k*64+a] = C[a][k]
    __shared__ float sAt[HID * HID];  // sAt[k*84+i] = A[i][k]
    __shared__ float sx[HID];
    __shared__ float se[OBS];

    const int b = blockIdx.x;
    const int t = threadIdx.x;
    const float* y = &Y[b * SL * OBS];

    for (int u = t; u < OBS * HID; u += 64) {
        const int a = u / HID, k = u % HID;
        sCt[k * OBS + a] = Cg[u];
    }
    for (int u = t; u < HID * HID; u += 64) {
        const int i = u / HID, k = u % HID;
        sAt[k * HID + i] = Ag[u];
    }
    sx[t] = 0.f;
    if (t < HID - OBS) sx[OBS + t] = 0.f;
    __syncthreads();

    const int ncv = *ncvp;
    float q = 0.f;

    for (int i = 0; i < SL; ++i) {
        const int s = (i < ncv) ? i : (ncv - 1);
        const float* Ws  = Wg   + s * OBS * OBS;
        const float* AKs = AKtg + s * OBS * HID;

        // e_t = y - C x
        float acc = 0.f;
        #pragma unroll 4
        for (int k = 0; k < HID; ++k) acc += sCt[k * OBS + t] * sx[k];
        const float e_t = y[i * OBS + t] - acc;
        se[t] = e_t;
        __syncthreads();

        // q += e^T W e
        float wacc = 0.f;
        #pragma unroll 4
        for (int k = 0; k < OBS; ++k) wacc += Ws[k * OBS + t] * se[k];
        q += e_t * wacc;

        // x' = A x + AK e  (lane t owns rows t and t+64)
        float ax1 = 0.f, k1 = 0.f;
        #pragma unroll 4
        for (int k = 0; k < HID; ++k) ax1 += sAt[k * HID + t] * sx[k];
        #pragma unroll 4
        for (int m = 0; m < OBS; ++m) k1 += AKs[m * HID + t] * se[m];
        float nx2 = 0.f;
        if (t < HID - OBS) {
            float ax2 = 0.f, k2 = 0.f;
            #pragma unroll 4
            for (int k = 0; k < HID; ++k) ax2 += sAt[k * HID + OBS + t] * sx[k];
            #pragma unroll 4
            for (int m = 0; m < OBS; ++m) k2 += AKs[m * HID + OBS + t] * se[m];
            nx2 = ax2 + k2;
        }
        __syncthreads();
        sx[t] = ax1 + k1;
        if (t < HID - OBS) sx[OBS + t] = nx2;
        __syncthreads();
    }

    #pragma unroll
    for (int m = 32; m >= 1; m >>= 1)
        q += __shfl_xor(q, m);
    if (t == 0) partials[b] = q;
}

// ---------------------------------------------------------------------------
__global__ void finalize_kernel(const float* __restrict__ partials,
                                float* __restrict__ out)
{
    const int t = threadIdx.x;
    float q = (t < BATCH) ? partials[t] : 0.0f;
    #pragma unroll
    for (int m = 32; m >= 1; m >>= 1)
        q += __shfl_xor(q, m);
    if (t == 0) out[0] = q * (1.0f / (float)(BATCH * SL * HID));
}

// ---------------------------------------------------------------------------
extern "C" void kernel_launch(void* const* d_in, const int* in_sizes, int n_in,
                              void* d_out, int out_size, void* d_ws, size_t ws_size,
                              hipStream_t stream)
{
    const float* Y = (const float*)d_in[0];   // (32, 3072) f32
    const float* A = (const float*)d_in[1];   // (84, 84)   f32
    const float* C = (const float*)d_in[2];   // (64, 84)   f32
    // d_in[3] = step (unused)

    float* ws = (float*)d_ws;
    float* Ktg  = ws;                          // SL*OBS*HID = 258048
    float* Wg   = Ktg  + SL * OBS * HID;       // SL*OBS*OBS = 196608
    float* AKtg = Wg   + SL * OBS * OBS;       // SL*OBS*HID = 258048
    float* partials = AKtg + SL * OBS * HID;   // 32
    int*   ncvp = (int*)(partials + BATCH);    // 1
    // total ~2.85 MB of ws

    (void)hipFuncSetAttribute((const void*)riccati_kernel,
                              hipFuncAttributeMaxDynamicSharedMemorySize,
                              SMEM_BYTES);

    riccati_kernel<<<1, 512, SMEM_BYTES, stream>>>(A, C, Ktg, Wg, ncvp);
    prep_kernel<<<SL, 256, 0, stream>>>(A, Ktg, ncvp, AKtg);
    sweep_kernel<<<BATCH, 64, 0, stream>>>(Y, A, C, AKtg, Wg, ncvp, partials);
    finalize_kernel<<<1, 64, 0, stream>>>(partials, (float*)d_out);
}

// Round 5
// 544.847 us; speedup vs baseline: 1.5284x; 1.5284x over previous
//
#include <hip/hip_runtime.h>

#define SL    48   // sequence length
#define OBS   64   // observation dim
#define HID   84   // hidden dim
#define BATCH 32
#define PTOL  1e-3f  // tol on max|dW|,|dK| between consecutive Riccati steps

// LDS layout (floats); every OFF*4 is 16B-aligned.
#define OFF_P   0        // 84 x 96 (swizzled chunks)
#define OFF_T2  8064     // 64 x 96  [aliased by U]
#define OFF_T   14208    // 84 x 64
#define OFF_U   8064     // 84 x 96 (alias of T2/T region; disjoint lifetime)
#define OFF_S   19584    // 64 x 64
#define OFF_K   23680    // 84 x 64
#define OFF_RB  29056    // 2 x (8 x 64) GJ pivot row panels (double buffer)
#define OFF_CB  30080    // 2 x (64 x 8) GJ pivot col panels (double buffer)
#define OFF_RED 31104    // 8
#define SMEM_F  31112
#define SMEM_BYTES (SMEM_F * 4)

__device__ __forceinline__ int swz(int row, int c) { return c ^ ((row >> 2) & 7); }

// NT-GEMM 4x4 tile: acc[r][s] += sum_k X[i0+r][k] * Y[j0+s][k], k = 4*KC.
template<int KC, int XS, bool XSW, int YS, bool YSW>
__device__ __forceinline__ void tile_nt(const float* __restrict__ X,
                                        const float* __restrict__ Y,
                                        int i0, int j0, float acc[4][4])
{
    const int xk = XSW ? ((i0 >> 2) & 7) : 0;
    const int yk = YSW ? ((j0 >> 2) & 7) : 0;
    #pragma unroll 4
    for (int c = 0; c < KC; ++c) {
        const int xc = (XSW ? (c ^ xk) : c) << 2;
        const int yc = (YSW ? (c ^ yk) : c) << 2;
        float4 a[4], b[4];
        #pragma unroll
        for (int r = 0; r < 4; ++r)
            a[r] = *reinterpret_cast<const float4*>(&X[(i0 + r) * XS + xc]);
        #pragma unroll
        for (int s = 0; s < 4; ++s)
            b[s] = *reinterpret_cast<const float4*>(&Y[(j0 + s) * YS + yc]);
        #pragma unroll
        for (int r = 0; r < 4; ++r)
            #pragma unroll
            for (int s = 0; s < 4; ++s)
                acc[r][s] += a[r].x * b[s].x + a[r].y * b[s].y
                           + a[r].z * b[s].z + a[r].w * b[s].w;
    }
}

__device__ __forceinline__ void inv4_inplace(float a[4][4])
{
    float o[4][4] = {{1,0,0,0},{0,1,0,0},{0,0,1,0},{0,0,0,1}};
    #pragma unroll
    for (int p = 0; p < 4; ++p) {
        const float f = 1.0f / a[p][p];
        #pragma unroll
        for (int c = 0; c < 4; ++c) { a[p][c] *= f; o[p][c] *= f; }
        #pragma unroll
        for (int r = 0; r < 4; ++r) {
            if (r == p) continue;
            const float g = a[r][p];
            #pragma unroll
            for (int c = 0; c < 4; ++c) { a[r][c] -= g * a[p][c]; o[r][c] -= g * o[p][c]; }
        }
    }
    #pragma unroll
    for (int r = 0; r < 4; ++r)
        #pragma unroll
        for (int c = 0; c < 4; ++c) a[r][c] = o[r][c];
}

// ---------------------------------------------------------------------------
// Phase 1: Riccati sweep. Single block, 512 threads, all-LDS working set.
// ---------------------------------------------------------------------------
__global__ __launch_bounds__(512)
void riccati_kernel(const float* __restrict__ Ag,   // HID x HID
                    const float* __restrict__ Cg,   // OBS x HID
                    float* __restrict__ Ktg,        // SL * OBS * HID
                    float* __restrict__ Wg,         // SL * OBS * OBS
                    int*   __restrict__ ncvp)
{
    extern __shared__ float smem[];
    float*  sP   = smem + OFF_P;
    float*  sT2  = smem + OFF_T2;
    float*  sT   = smem + OFF_T;
    float*  sU   = smem + OFF_U;
    float*  sS   = smem + OFF_S;
    float*  sK   = smem + OFF_K;
    float*  rbuf = smem + OFF_RB;   // [2][8*64]
    float*  cbuf = smem + OFF_CB;   // [2][64*8]
    float*  sRed = smem + OFF_RED;
    float4* sP4  = reinterpret_cast<float4*>(sP);
    float4* sT24 = reinterpret_cast<float4*>(sT2);
    float4* sT4  = reinterpret_cast<float4*>(sT);
    float4* sU4  = reinterpret_cast<float4*>(sU);
    float4* sS4  = reinterpret_cast<float4*>(sS);
    float4* sK4  = reinterpret_cast<float4*>(sK);

    const int t = threadIdx.x;

    // P = I
    for (int u = t; u < HID * 24; u += 512) {
        const int row = u / 24, pc = u % 24;
        const int lc = pc ^ ((row >> 2) & 7);
        float4 v = make_float4(0.f, 0.f, 0.f, 0.f);
        if (lc < 21) {
            const int base = lc * 4;
            if (row == base)     v.x = 1.f;
            if (row == base + 1) v.y = 1.f;
            if (row == base + 2) v.z = 1.f;
            if (row == base + 3) v.w = 1.f;
        }
        sP4[row * 24 + pc] = v;
    }
    __syncthreads();

    int ncv = SL;
    for (int step = 0; step < SL; ++step) {
        // ---- P1: T2 = C * P ; T = T2^T
        if (t < 336) {
            const int a0 = (t / 21) * 4, i0 = (t % 21) * 4;
            float acc[4][4] = {};
            tile_nt<21, HID, false, 96, true>(Cg, sP, a0, i0, acc);
            #pragma unroll
            for (int r = 0; r < 4; ++r)
                sT24[(a0 + r) * 24 + swz(a0 + r, i0 >> 2)] =
                    make_float4(acc[r][0], acc[r][1], acc[r][2], acc[r][3]);
            #pragma unroll
            for (int s = 0; s < 4; ++s)
                sT4[(i0 + s) * 16 + swz(i0 + s, a0 >> 2)] =
                    make_float4(acc[0][s], acc[1][s], acc[2][s], acc[3][s]);
        }
        __syncthreads();

        // ---- P2: S = T2 * C^T; also seed GJ group-0 pivot panels
        if (t < 256) {
            const int a0 = (t / 16) * 4, b0 = (t % 16) * 4;
            float acc[4][4] = {};
            tile_nt<21, 96, true, HID, false>(sT2, Cg, a0, b0, acc);
            #pragma unroll
            for (int r = 0; r < 4; ++r)
                sS4[(a0 + r) * 16 + swz(a0 + r, b0 >> 2)] =
                    make_float4(acc[r][0], acc[r][1], acc[r][2], acc[r][3]);
            if (a0 < 8) {
                #pragma unroll
                for (int r = 0; r < 4; ++r)
                    #pragma unroll
                    for (int s = 0; s < 4; ++s)
                        rbuf[(a0 + r) * 64 + b0 + s] = acc[r][s];
            }
            if (b0 < 8) {
                #pragma unroll
                for (int r = 0; r < 4; ++r)
                    #pragma unroll
                    for (int s = 0; s < 4; ++s)
                        cbuf[(a0 + r) * 8 + b0 + s] = acc[r][s];
            }
        }
        __syncthreads();

        // ---- P3: block-8 Gauss-Jordan inverse of S, 1 barrier/group
        for (int g = 0; g < 8; ++g) {
            const int p0 = g * 8;
            const float* rb  = rbuf + (g & 1) * 512;
            const float* cb  = cbuf + (g & 1) * 512;
            float* rbn = rbuf + ((g + 1) & 1) * 512;
            float* cbn = cbuf + ((g + 1) & 1) * 512;

            // replicated 8x8 pivot inverse via Schur of 4x4 blocks
            float pinv[8][8];
            {
                float Ai[4][4], F[4][4], E[4][4], Sc[4][4], G[4][4];
                #pragma unroll
                for (int r = 0; r < 4; ++r)
                    #pragma unroll
                    for (int c = 0; c < 4; ++c) Ai[r][c] = rb[r * 64 + p0 + c];
                inv4_inplace(Ai);
                #pragma unroll
                for (int r = 0; r < 4; ++r)
                    #pragma unroll
                    for (int c = 0; c < 4; ++c) {
                        float s = 0.f;
                        #pragma unroll
                        for (int m = 0; m < 4; ++m) s += Ai[r][m] * rb[m * 64 + p0 + 4 + c];
                        F[r][c] = s;
                    }
                #pragma unroll
                for (int r = 0; r < 4; ++r)
                    #pragma unroll
                    for (int c = 0; c < 4; ++c) {
                        float s = rb[(4 + r) * 64 + p0 + 4 + c];
                        #pragma unroll
                        for (int m = 0; m < 4; ++m) s -= rb[(4 + r) * 64 + p0 + m] * F[m][c];
                        Sc[r][c] = s;
                    }
                inv4_inplace(Sc);
                #pragma unroll
                for (int r = 0; r < 4; ++r)
                    #pragma unroll
                    for (int c = 0; c < 4; ++c) {
                        float s = 0.f;
                        #pragma unroll
                        for (int m = 0; m < 4; ++m) s += rb[(4 + r) * 64 + p0 + m] * Ai[m][c];
                        E[r][c] = s;
                    }
                #pragma unroll
                for (int r = 0; r < 4; ++r)
                    #pragma unroll
                    for (int c = 0; c < 4; ++c) {
                        float s = 0.f;
                        #pragma unroll
                        for (int m = 0; m < 4; ++m) s += Sc[r][m] * E[m][c];
                        G[r][c] = s;
                    }
                #pragma unroll
                for (int r = 0; r < 4; ++r)
                    #pragma unroll
                    for (int c = 0; c < 4; ++c) {
                        float tr = 0.f, tl = 0.f;
                        #pragma unroll
                        for (int m = 0; m < 4; ++m) { tr += F[r][m] * Sc[m][c]; tl += F[r][m] * G[m][c]; }
                        pinv[r][4 + c] = -tr;
                        pinv[r][c]     = Ai[r][c] + tl;
                        pinv[4 + r][c]     = -G[r][c];
                        pinv[4 + r][4 + c] = Sc[r][c];
                    }
            }

            // update: thread owns (i, c0) and (i, c0+8)
            const int i = t >> 3, c0 = t & 7;
            const bool piv = (i >= p0) && (i < p0 + 8);
            float e8[8];
            if (!piv) {
                #pragma unroll
                for (int l = 0; l < 8; ++l) {
                    float s = 0.f;
                    #pragma unroll
                    for (int m = 0; m < 8; ++m) s += cb[i * 8 + m] * pinv[m][l];
                    e8[l] = s;
                }
            }
            #pragma unroll
            for (int rep = 0; rep < 2; ++rep) {
                const int c = c0 + rep * 8;
                float o[4];
                if (piv) {
                    const int r = i - p0;
                    if (c == 2 * g) {
                        o[0] = pinv[r][0]; o[1] = pinv[r][1]; o[2] = pinv[r][2]; o[3] = pinv[r][3];
                    } else if (c == 2 * g + 1) {
                        o[0] = pinv[r][4]; o[1] = pinv[r][5]; o[2] = pinv[r][6]; o[3] = pinv[r][7];
                    } else {
                        #pragma unroll
                        for (int jj = 0; jj < 4; ++jj) {
                            float s = 0.f;
                            #pragma unroll
                            for (int l = 0; l < 8; ++l) s += pinv[r][l] * rb[l * 64 + 4 * c + jj];
                            o[jj] = s;
                        }
                    }
                } else {
                    if (c == 2 * g) {
                        o[0] = -e8[0]; o[1] = -e8[1]; o[2] = -e8[2]; o[3] = -e8[3];
                    } else if (c == 2 * g + 1) {
                        o[0] = -e8[4]; o[1] = -e8[5]; o[2] = -e8[6]; o[3] = -e8[7];
                    } else {
                        const float4 old = sS4[i * 16 + swz(i, c)];
                        o[0] = old.x; o[1] = old.y; o[2] = old.z; o[3] = old.w;
                        #pragma unroll
                        for (int l = 0; l < 8; ++l) {
                            const float el = e8[l];
                            #pragma unroll
                            for (int jj = 0; jj < 4; ++jj) o[jj] -= el * rbuf[(g & 1) * 512 + l * 64 + 4 * c + jj];
                        }
                    }
                }
                sS4[i * 16 + swz(i, c)] = make_float4(o[0], o[1], o[2], o[3]);
                if (g < 7) {
                    // seed next group's pivot panels from post-update values
                    if (i >= p0 + 8 && i < p0 + 16) {
                        #pragma unroll
                        for (int jj = 0; jj < 4; ++jj)
                            rbn[(i - p0 - 8) * 64 + 4 * c + jj] = o[jj];
                    }
                    if (c == 2 * g + 2) {
                        #pragma unroll
                        for (int jj = 0; jj < 4; ++jj) cbn[i * 8 + jj] = o[jj];
                    } else if (c == 2 * g + 3) {
                        #pragma unroll
                        for (int jj = 0; jj < 4; ++jj) cbn[i * 8 + 4 + jj] = o[jj];
                    }
                }
            }
            __syncthreads();
        }

        // ---- P4: K = T*W -> sK + Ktg; stream W; convergence on dK,dW
        float maxd = 0.0f;
        float* Ktstep = Ktg + step * OBS * HID;
        const float* Ktprev = Ktg + (step - 1) * OBS * HID;
        if (t < 336) {
            const int i0 = (t / 16) * 4, j0 = (t % 16) * 4;
            float acc[4][4] = {};
            tile_nt<16, 64, true, 64, true>(sT, sS, i0, j0, acc);
            #pragma unroll
            for (int r = 0; r < 4; ++r)
                sK4[(i0 + r) * 16 + swz(i0 + r, j0 >> 2)] =
                    make_float4(acc[r][0], acc[r][1], acc[r][2], acc[r][3]);
            #pragma unroll
            for (int s = 0; s < 4; ++s) {
                const float4 nv = make_float4(acc[0][s], acc[1][s], acc[2][s], acc[3][s]);
                if (step > 0) {
                    const float4 ov =
                        *reinterpret_cast<const float4*>(&Ktprev[(j0 + s) * HID + i0]);
                    maxd = fmaxf(maxd, fmaxf(fmaxf(fabsf(nv.x - ov.x), fabsf(nv.y - ov.y)),
                                             fmaxf(fabsf(nv.z - ov.z), fabsf(nv.w - ov.w))));
                }
                *reinterpret_cast<float4*>(&Ktstep[(j0 + s) * HID + i0]) = nv;
            }
        }
        {
            float* Wstep = Wg + step * OBS * OBS;
            const float* Wprev = Wg + (step - 1) * OBS * OBS;
            #pragma unroll
            for (int rep = 0; rep < 2; ++rep) {
                const int u = t + rep * 512;
                const int row = u >> 4, c = u & 15;
                const float4 nv = sS4[row * 16 + swz(row, c)];
                if (step > 0) {
                    const float4 ov = reinterpret_cast<const float4*>(Wprev)[row * 16 + c];
                    maxd = fmaxf(maxd, fmaxf(fmaxf(fabsf(nv.x - ov.x), fabsf(nv.y - ov.y)),
                                             fmaxf(fabsf(nv.z - ov.z), fabsf(nv.w - ov.w))));
                }
                reinterpret_cast<float4*>(Wstep)[row * 16 + c] = nv;
            }
        }
        #pragma unroll
        for (int mo = 32; mo >= 1; mo >>= 1)
            maxd = fmaxf(maxd, __shfl_xor(maxd, mo));
        if ((t & 63) == 0) sRed[t >> 6] = maxd;
        __syncthreads();
        float mm = sRed[0];
        #pragma unroll
        for (int w = 1; w < 8; ++w) mm = fmaxf(mm, sRed[w]);
        if (step > 0 && mm < PTOL) { ncv = step + 1; break; }
        if (step == SL - 1) break;

        // ---- P5: PF = P - K*T^T (in place)
        if (t < 441) {
            const int i0 = (t / 21) * 4, j0 = (t % 21) * 4;
            float acc[4][4] = {};
            tile_nt<16, 64, true, 64, true>(sK, sT, i0, j0, acc);
            #pragma unroll
            for (int r = 0; r < 4; ++r) {
                float4* p = &sP4[(i0 + r) * 24 + swz(i0 + r, j0 >> 2)];
                float4 v = *p;
                v.x -= acc[r][0]; v.y -= acc[r][1]; v.z -= acc[r][2]; v.w -= acc[r][3];
                *p = v;
            }
        }
        __syncthreads();

        // ---- P6: U = A * PF (PF symmetric)
        if (t < 441) {
            const int i0 = (t / 21) * 4, j0 = (t % 21) * 4;
            float acc[4][4] = {};
            tile_nt<21, HID, false, 96, true>(Ag, sP, i0, j0, acc);
            #pragma unroll
            for (int r = 0; r < 4; ++r)
                sU4[(i0 + r) * 24 + swz(i0 + r, j0 >> 2)] =
                    make_float4(acc[r][0], acc[r][1], acc[r][2], acc[r][3]);
        }
        __syncthreads();

        // ---- P7: P = A * U^T + I
        if (t < 441) {
            const int i0 = (t / 21) * 4, j0 = (t % 21) * 4;
            float acc[4][4] = {};
            tile_nt<21, HID, false, 96, true>(Ag, sU, i0, j0, acc);
            #pragma unroll
            for (int r = 0; r < 4; ++r) {
                float4 v = make_float4(acc[r][0], acc[r][1], acc[r][2], acc[r][3]);
                if (i0 + r == j0 + 0) v.x += 1.f;
                if (i0 + r == j0 + 1) v.y += 1.f;
                if (i0 + r == j0 + 2) v.z += 1.f;
                if (i0 + r == j0 + 3) v.w += 1.f;
                sP4[(i0 + r) * 24 + swz(i0 + r, j0 >> 2)] = v;
            }
        }
        __syncthreads();
    }

    if (t == 0) *ncvp = ncv;
}

// ---------------------------------------------------------------------------
// Phase 1b: AK_s = A * K_s for s < ncv, stored transposed (OBS x HID).
// ---------------------------------------------------------------------------
__global__ __launch_bounds__(256)
void prep_kernel(const float* __restrict__ Ag,
                 const float* __restrict__ Ktg,
                 const int*   __restrict__ ncvp,
                 float* __restrict__ AKtg)
{
    const int s = blockIdx.x;
    if (s >= *ncvp) return;
    const float* Kts  = Ktg  + s * OBS * HID;
    float*       AKts = AKtg + s * OBS * HID;
    for (int u = threadIdx.x; u < 336; u += 256) {
        const int i0 = (u / 16) * 4, j0 = (u % 16) * 4;
        float acc[4][4] = {};
        tile_nt<21, HID, false, HID, false>(Ag, Kts, i0, j0, acc);
        #pragma unroll
        for (int c = 0; c < 4; ++c)
            *reinterpret_cast<float4*>(&AKts[(j0 + c) * HID + i0]) =
                make_float4(acc[0][c], acc[1][c], acc[2][c], acc[3][c]);
    }
}

// ---------------------------------------------------------------------------
// Phase 2: per-batch Kalman sweep. 256 threads (4 waves), split-K GEMVs.
// x' = A x + AK e;  q += e^T W e  (q kept per-lane in registers).
// ---------------------------------------------------------------------------
__global__ __launch_bounds__(256)
void sweep_kernel(const float* __restrict__ Y,     // BATCH x (SL*OBS)
                  const float* __restrict__ Ag,
                  const float* __restrict__ Cg,
                  const float* __restrict__ AKtg,  // SL * OBS * HID
                  const float* __restrict__ Wg,    // SL * OBS * OBS
                  const int*   __restrict__ ncvp,
                  float* __restrict__ partials)
{
    __shared__ float sCt[HID * OBS];  // [k][o] = C[o][k]
    __shared__ float sAt[HID * HID];  // [k][i] = A[i][k]
    __shared__ float sx[HID];
    __shared__ float se[OBS];
    __shared__ float pA[4][OBS];
    __shared__ float pC[2][HID];
    __shared__ float wq[4];

    const int b = blockIdx.x;
    const int t = threadIdx.x;
    const float* y = &Y[b * SL * OBS];

    for (int u = t; u < OBS * HID; u += 256) {
        const int a = u / HID, k = u % HID;
        sCt[k * OBS + a] = Cg[u];
    }
    for (int u = t; u < HID * HID; u += 256) {
        const int i = u / HID, k = u % HID;
        sAt[k * HID + i] = Ag[u];
    }
    if (t < HID) sx[t] = 0.f;
    __syncthreads();

    const int o  = t & 63;   // output for C-row / W phases
    const int sg = t >> 6;   // 0..3 (k-segment)
    const int L  = t & 127;  // output for x'-phase
    const int s2 = t >> 7;   // 0..1 (k-segment)
    const int ncv = *ncvp;
    float q = 0.f;

    for (int i = 0; i < SL; ++i) {
        const int s = (i < ncv) ? i : (ncv - 1);
        const float* Ws  = Wg   + s * OBS * OBS;
        const float* AKs = AKtg + s * OBS * HID;

        // phase 1: partials of C·x (4-way) and A·x (2-way)
        float a1 = 0.f;
        #pragma unroll 7
        for (int kk = 0; kk < 21; ++kk) {
            const int k = sg * 21 + kk;
            a1 += sCt[k * OBS + o] * sx[k];
        }
        pA[sg][o] = a1;
        float c1 = 0.f;
        if (L < HID) {
            #pragma unroll 6
            for (int kk = 0; kk < 42; ++kk) {
                const int k = s2 * 42 + kk;
                c1 += sAt[k * HID + L] * sx[k];
            }
        }
        __syncthreads();

        // phase 2: e = y - C·x
        if (t < OBS)
            se[t] = y[i * OBS + t] - (pA[0][t] + pA[1][t] + pA[2][t] + pA[3][t]);
        __syncthreads();

        // phase 3: q-partial (W sym: col o) + AK·e partial
        float w1 = 0.f;
        #pragma unroll 4
        for (int m = 0; m < 16; ++m) {
            const int k = sg * 16 + m;
            w1 += Ws[k * OBS + o] * se[k];
        }
        q += se[o] * w1;
        if (L < HID) {
            #pragma unroll 4
            for (int m = 0; m < 32; ++m) {
                const int mm = s2 * 32 + m;
                c1 += AKs[mm * HID + L] * se[mm];
            }
            pC[s2][L] = c1;
        }
        __syncthreads();

        // phase 4: x' commit
        if (t < HID) sx[t] = pC[0][t] + pC[1][t];
        __syncthreads();
    }

    #pragma unroll
    for (int m = 32; m >= 1; m >>= 1)
        q += __shfl_xor(q, m);
    if ((t & 63) == 0) wq[t >> 6] = q;
    __syncthreads();
    if (t == 0) partials[b] = wq[0] + wq[1] + wq[2] + wq[3];
}

// ---------------------------------------------------------------------------
__global__ void finalize_kernel(const float* __restrict__ partials,
                                float* __restrict__ out)
{
    const int t = threadIdx.x;
    float q = (t < BATCH) ? partials[t] : 0.0f;
    #pragma unroll
    for (int m = 32; m >= 1; m >>= 1)
        q += __shfl_xor(q, m);
    if (t == 0) out[0] = q * (1.0f / (float)(BATCH * SL * HID));
}

// ---------------------------------------------------------------------------
extern "C" void kernel_launch(void* const* d_in, const int* in_sizes, int n_in,
                              void* d_out, int out_size, void* d_ws, size_t ws_size,
                              hipStream_t stream)
{
    const float* Y = (const float*)d_in[0];   // (32, 3072) f32
    const float* A = (const float*)d_in[1];   // (84, 84)   f32
    const float* C = (const float*)d_in[2];   // (64, 84)   f32
    // d_in[3] = step (unused)

    float* ws = (float*)d_ws;
    float* Ktg  = ws;                          // SL*OBS*HID = 258048
    float* Wg   = Ktg  + SL * OBS * HID;       // SL*OBS*OBS = 196608
    float* AKtg = Wg   + SL * OBS * OBS;       // SL*OBS*HID = 258048
    float* partials = AKtg + SL * OBS * HID;   // 32
    int*   ncvp = (int*)(partials + BATCH);    // 1

    (void)hipFuncSetAttribute((const void*)riccati_kernel,
                              hipFuncAttributeMaxDynamicSharedMemorySize,
                              SMEM_BYTES);

    riccati_kernel<<<1, 512, SMEM_BYTES, stream>>>(A, C, Ktg, Wg, ncvp);
    prep_kernel<<<SL, 256, 0, stream>>>(A, Ktg, ncvp, AKtg);
    sweep_kernel<<<BATCH, 256, 0, stream>>>(Y, A, C, AKtg, Wg, ncvp, partials);
    finalize_kernel<<<1, 64, 0, stream>>>(partials, (float*)d_out);
}

// Round 6
// 544.309 us; speedup vs baseline: 1.5299x; 1.0010x over previous
//
#include <hip/hip_runtime.h>

#define SL    48   // sequence length
#define OBS   64   // observation dim
#define HID   84   // hidden dim
#define BATCH 32
#define PTOL  1e-3f  // tol on max|dW|,|dAK| between consecutive Riccati steps

// LDS layout (floats); every OFF*4 is 16B-aligned.
#define OFF_P   0        // 84 x 96 swizzled (P, symmetric)
#define OFF_T2  8064     // 64 x 96 swizzled (T2 = C*P)
#define OFF_G1  14208    // 84 x 96 swizzled (G1 = A*P)
#define OFF_V   22272    // 84 x 64 swizzled (V = A*P*C^T)
#define OFF_S   27648    // 64 x 64 swizzled (S -> W in place)
#define OFF_AK  31744    // 84 x 64 swizzled (AK = V*W)
#define OFF_RB  37120    // 2 x (4 x 64) GJ pivot row panels (double buffer)
#define OFF_CB  37632    // 2 x (64 x 4) GJ pivot col panels (double buffer)
#define OFF_RED 38144    // 8
#define SMEM_F  38152
#define SMEM_BYTES (SMEM_F * 4)   // 152,608 B < 160 KiB

__device__ __forceinline__ int swz(int row, int c) { return c ^ ((row >> 2) & 7); }

// NT-GEMM 4x4 tile: acc[r][s] += sum_k X[i0+r][k] * Y[j0+s][k], k = 4*KC.
template<int KC, int XS, bool XSW, int YS, bool YSW>
__device__ __forceinline__ void tile_nt(const float* __restrict__ X,
                                        const float* __restrict__ Y,
                                        int i0, int j0, float acc[4][4])
{
    const int xk = XSW ? ((i0 >> 2) & 7) : 0;
    const int yk = YSW ? ((j0 >> 2) & 7) : 0;
    #pragma unroll 4
    for (int c = 0; c < KC; ++c) {
        const int xc = (XSW ? (c ^ xk) : c) << 2;
        const int yc = (YSW ? (c ^ yk) : c) << 2;
        float4 a[4], b[4];
        #pragma unroll
        for (int r = 0; r < 4; ++r)
            a[r] = *reinterpret_cast<const float4*>(&X[(i0 + r) * XS + xc]);
        #pragma unroll
        for (int s = 0; s < 4; ++s)
            b[s] = *reinterpret_cast<const float4*>(&Y[(j0 + s) * YS + yc]);
        #pragma unroll
        for (int r = 0; r < 4; ++r)
            #pragma unroll
            for (int s = 0; s < 4; ++s)
                acc[r][s] += a[r].x * b[s].x + a[r].y * b[s].y
                           + a[r].z * b[s].z + a[r].w * b[s].w;
    }
}

__device__ __forceinline__ void inv4_inplace(float a[4][4])
{
    float o[4][4] = {{1,0,0,0},{0,1,0,0},{0,0,1,0},{0,0,0,1}};
    #pragma unroll
    for (int p = 0; p < 4; ++p) {
        const float f = 1.0f / a[p][p];
        #pragma unroll
        for (int c = 0; c < 4; ++c) { a[p][c] *= f; o[p][c] *= f; }
        #pragma unroll
        for (int r = 0; r < 4; ++r) {
            if (r == p) continue;
            const float g = a[r][p];
            #pragma unroll
            for (int c = 0; c < 4; ++c) { a[r][c] -= g * a[p][c]; o[r][c] -= g * o[p][c]; }
        }
    }
    #pragma unroll
    for (int r = 0; r < 4; ++r)
        #pragma unroll
        for (int c = 0; c < 4; ++c) a[r][c] = o[r][c];
}

// ---------------------------------------------------------------------------
// Phase 1: Riccati sweep. Single block, 512 threads, all-LDS working set.
// Per step emits AK^T = (A*K)^T and W = S^{-1} (exactly what the sweep uses).
// Update: T2=C*P; {S=T2*C^T, V=A*T2^T, G1=A*P}; W=S^-1; AK=V*W;
//         P' = G1*A^T - AK*V^T + I.
// ---------------------------------------------------------------------------
__global__ __launch_bounds__(512)
void riccati_kernel(const float* __restrict__ Ag,   // HID x HID
                    const float* __restrict__ Cg,   // OBS x HID
                    float* __restrict__ AKtg,       // SL * OBS * HID
                    float* __restrict__ Wg,         // SL * OBS * OBS
                    int*   __restrict__ ncvp)
{
    extern __shared__ float smem[];
    float*  sP   = smem + OFF_P;
    float*  sT2  = smem + OFF_T2;
    float*  sG1  = smem + OFF_G1;
    float*  sV   = smem + OFF_V;
    float*  sS   = smem + OFF_S;
    float*  sAK  = smem + OFF_AK;
    float*  rbuf = smem + OFF_RB;   // [2][4*64]
    float*  cbuf = smem + OFF_CB;   // [2][64*4]
    float*  sRed = smem + OFF_RED;
    float4* sP4  = reinterpret_cast<float4*>(sP);
    float4* sT24 = reinterpret_cast<float4*>(sT2);
    float4* sG14 = reinterpret_cast<float4*>(sG1);
    float4* sV4  = reinterpret_cast<float4*>(sV);
    float4* sS4  = reinterpret_cast<float4*>(sS);
    float4* sAK4 = reinterpret_cast<float4*>(sAK);

    const int t = threadIdx.x;

    // P = I
    for (int u = t; u < HID * 24; u += 512) {
        const int row = u / 24, pc = u % 24;
        const int lc = pc ^ ((row >> 2) & 7);
        float4 v = make_float4(0.f, 0.f, 0.f, 0.f);
        if (lc < 21) {
            const int base = lc * 4;
            if (row == base)     v.x = 1.f;
            if (row == base + 1) v.y = 1.f;
            if (row == base + 2) v.z = 1.f;
            if (row == base + 3) v.w = 1.f;
        }
        sP4[row * 24 + pc] = v;
    }
    __syncthreads();

    int ncv = SL;
    for (int step = 0; step < SL; ++step) {
        // ---- P1: T2 = C * P  (64 x 84)
        if (t < 336) {
            const int a0 = (t / 21) * 4, i0 = (t % 21) * 4;
            float acc[4][4] = {};
            tile_nt<21, HID, false, 96, true>(Cg, sP, a0, i0, acc);
            #pragma unroll
            for (int r = 0; r < 4; ++r)
                sT24[(a0 + r) * 24 + swz(a0 + r, i0 >> 2)] =
                    make_float4(acc[r][0], acc[r][1], acc[r][2], acc[r][3]);
        }
        __syncthreads();

        // ---- P2: S = T2*C^T (256 tiles), V = A*T2^T (336), G1 = A*P (441)
        //         also seed GJ group-0 pivot panels from S tiles
        for (int u = t; u < 1033; u += 512) {
            if (u < 256) {
                const int a0 = (u / 16) * 4, b0 = (u % 16) * 4;
                float acc[4][4] = {};
                tile_nt<21, 96, true, HID, false>(sT2, Cg, a0, b0, acc);
                #pragma unroll
                for (int r = 0; r < 4; ++r)
                    sS4[(a0 + r) * 16 + swz(a0 + r, b0 >> 2)] =
                        make_float4(acc[r][0], acc[r][1], acc[r][2], acc[r][3]);
                if (a0 < 4) {
                    #pragma unroll
                    for (int r = 0; r < 4; ++r)
                        #pragma unroll
                        for (int s = 0; s < 4; ++s)
                            rbuf[(a0 + r) * 64 + b0 + s] = acc[r][s];
                }
                if (b0 == 0) {
                    #pragma unroll
                    for (int r = 0; r < 4; ++r)
                        #pragma unroll
                        for (int s = 0; s < 4; ++s)
                            cbuf[(a0 + r) * 4 + s] = acc[r][s];
                }
            } else if (u < 592) {
                const int v = u - 256;
                const int i0 = (v / 16) * 4, j0 = (v % 16) * 4;
                float acc[4][4] = {};
                tile_nt<21, HID, false, 96, true>(Ag, sT2, i0, j0, acc);
                #pragma unroll
                for (int r = 0; r < 4; ++r)
                    sV4[(i0 + r) * 16 + swz(i0 + r, j0 >> 2)] =
                        make_float4(acc[r][0], acc[r][1], acc[r][2], acc[r][3]);
            } else {
                const int w = u - 592;
                const int i0 = (w / 21) * 4, j0 = (w % 21) * 4;
                float acc[4][4] = {};
                tile_nt<21, HID, false, 96, true>(Ag, sP, i0, j0, acc);
                #pragma unroll
                for (int r = 0; r < 4; ++r)
                    sG14[(i0 + r) * 24 + swz(i0 + r, j0 >> 2)] =
                        make_float4(acc[r][0], acc[r][1], acc[r][2], acc[r][3]);
            }
        }
        __syncthreads();

        // ---- P3: block-4 Gauss-Jordan inverse of S (SPD), 1 barrier/group
        for (int g = 0; g < 16; ++g) {
            const int p0 = g * 4;
            const float* rb  = rbuf + (g & 1) * 256;
            const float* cb  = cbuf + (g & 1) * 256;
            float* rbn = rbuf + ((g + 1) & 1) * 256;
            float* cbn = cbuf + ((g + 1) & 1) * 256;

            // replicated 4x4 pivot inverse
            float m[4][4];
            #pragma unroll
            for (int r = 0; r < 4; ++r)
                #pragma unroll
                for (int c = 0; c < 4; ++c) m[r][c] = rb[r * 64 + p0 + c];
            inv4_inplace(m);

            const int i = t >> 3, c0 = t & 7;
            const bool piv = (i >= p0) && (i < p0 + 4);
            float e4[4];
            if (!piv) {
                #pragma unroll
                for (int l = 0; l < 4; ++l) {
                    float s = 0.f;
                    #pragma unroll
                    for (int mm = 0; mm < 4; ++mm) s += cb[i * 4 + mm] * m[mm][l];
                    e4[l] = s;
                }
            }
            #pragma unroll
            for (int rep = 0; rep < 2; ++rep) {
                const int c = c0 + rep * 8;
                float o[4];
                if (piv) {
                    const int r = i - p0;
                    if (c == g) {
                        o[0] = m[r][0]; o[1] = m[r][1]; o[2] = m[r][2]; o[3] = m[r][3];
                    } else {
                        #pragma unroll
                        for (int jj = 0; jj < 4; ++jj) {
                            float s = 0.f;
                            #pragma unroll
                            for (int l = 0; l < 4; ++l) s += m[r][l] * rb[l * 64 + 4 * c + jj];
                            o[jj] = s;
                        }
                    }
                } else {
                    if (c == g) {
                        o[0] = -e4[0]; o[1] = -e4[1]; o[2] = -e4[2]; o[3] = -e4[3];
                    } else {
                        const float4 old = sS4[i * 16 + swz(i, c)];
                        o[0] = old.x; o[1] = old.y; o[2] = old.z; o[3] = old.w;
                        #pragma unroll
                        for (int l = 0; l < 4; ++l) {
                            const float el = e4[l];
                            #pragma unroll
                            for (int jj = 0; jj < 4; ++jj) o[jj] -= el * rb[l * 64 + 4 * c + jj];
                        }
                    }
                }
                sS4[i * 16 + swz(i, c)] = make_float4(o[0], o[1], o[2], o[3]);
                if (g < 15) {
                    if (i >= p0 + 4 && i < p0 + 8) {
                        #pragma unroll
                        for (int jj = 0; jj < 4; ++jj)
                            rbn[(i - p0 - 4) * 64 + 4 * c + jj] = o[jj];
                    }
                    if (c == g + 1) {
                        #pragma unroll
                        for (int jj = 0; jj < 4; ++jj) cbn[i * 4 + jj] = o[jj];
                    }
                }
            }
            __syncthreads();
        }

        // ---- P4: AK = V*W -> sAK + AKtg (transposed); stream W; convergence
        float maxd = 0.0f;
        float* AKtstep = AKtg + step * OBS * HID;
        const float* AKtprev = AKtg + (step - 1) * OBS * HID;
        if (t < 336) {
            const int i0 = (t / 16) * 4, j0 = (t % 16) * 4;
            float acc[4][4] = {};
            tile_nt<16, 64, true, 64, true>(sV, sS, i0, j0, acc);
            #pragma unroll
            for (int r = 0; r < 4; ++r)
                sAK4[(i0 + r) * 16 + swz(i0 + r, j0 >> 2)] =
                    make_float4(acc[r][0], acc[r][1], acc[r][2], acc[r][3]);
            #pragma unroll
            for (int s = 0; s < 4; ++s) {
                const float4 nv = make_float4(acc[0][s], acc[1][s], acc[2][s], acc[3][s]);
                if (step > 0) {
                    const float4 ov =
                        *reinterpret_cast<const float4*>(&AKtprev[(j0 + s) * HID + i0]);
                    maxd = fmaxf(maxd, fmaxf(fmaxf(fabsf(nv.x - ov.x), fabsf(nv.y - ov.y)),
                                             fmaxf(fabsf(nv.z - ov.z), fabsf(nv.w - ov.w))));
                }
                *reinterpret_cast<float4*>(&AKtstep[(j0 + s) * HID + i0]) = nv;
            }
        }
        {
            float* Wstep = Wg + step * OBS * OBS;
            const float* Wprev = Wg + (step - 1) * OBS * OBS;
            #pragma unroll
            for (int rep = 0; rep < 2; ++rep) {
                const int u = t + rep * 512;
                const int row = u >> 4, c = u & 15;
                const float4 nv = sS4[row * 16 + swz(row, c)];
                if (step > 0) {
                    const float4 ov = reinterpret_cast<const float4*>(Wprev)[row * 16 + c];
                    maxd = fmaxf(maxd, fmaxf(fmaxf(fabsf(nv.x - ov.x), fabsf(nv.y - ov.y)),
                                             fmaxf(fabsf(nv.z - ov.z), fabsf(nv.w - ov.w))));
                }
                reinterpret_cast<float4*>(Wstep)[row * 16 + c] = nv;
            }
        }
        #pragma unroll
        for (int mo = 32; mo >= 1; mo >>= 1)
            maxd = fmaxf(maxd, __shfl_xor(maxd, mo));
        if ((t & 63) == 0) sRed[t >> 6] = maxd;
        __syncthreads();
        float mm = sRed[0];
        #pragma unroll
        for (int w = 1; w < 8; ++w) mm = fmaxf(mm, sRed[w]);
        if (step > 0 && mm < PTOL) { ncv = step + 1; break; }
        if (step == SL - 1) break;

        // ---- P5: P' = G1*A^T - AK*V^T + I  (writes sP; G1/AK/V are the sources)
        if (t < 441) {
            const int i0 = (t / 21) * 4, j0 = (t % 21) * 4;
            float a1[4][4] = {}, a2[4][4] = {};
            tile_nt<21, 96, true, HID, false>(sG1, Ag, i0, j0, a1);
            tile_nt<16, 64, true, 64, true>(sAK, sV, i0, j0, a2);
            #pragma unroll
            for (int r = 0; r < 4; ++r) {
                float4 v = make_float4(a1[r][0] - a2[r][0], a1[r][1] - a2[r][1],
                                       a1[r][2] - a2[r][2], a1[r][3] - a2[r][3]);
                if (i0 + r == j0 + 0) v.x += 1.f;
                if (i0 + r == j0 + 1) v.y += 1.f;
                if (i0 + r == j0 + 2) v.z += 1.f;
                if (i0 + r == j0 + 3) v.w += 1.f;
                sP4[(i0 + r) * 24 + swz(i0 + r, j0 >> 2)] = v;
            }
        }
        __syncthreads();
    }

    if (t == 0) *ncvp = ncv;
}

// ---------------------------------------------------------------------------
// Phase 2: per-batch Kalman sweep. 256 threads (4 waves), split-K GEMVs.
// x' = A x + AK e;  q += e^T W e  (q kept per-lane in registers).
// ---------------------------------------------------------------------------
__global__ __launch_bounds__(256)
void sweep_kernel(const float* __restrict__ Y,     // BATCH x (SL*OBS)
                  const float* __restrict__ Ag,
                  const float* __restrict__ Cg,
                  const float* __restrict__ AKtg,  // SL * OBS * HID
                  const float* __restrict__ Wg,    // SL * OBS * OBS
                  const int*   __restrict__ ncvp,
                  float* __restrict__ partials)
{
    __shared__ float sCt[HID * OBS];  // [k][o] = C[o][k]
    __shared__ float sAt[HID * HID];  // [k][i] = A[i][k]
    __shared__ float sx[HID];
    __shared__ float se[OBS];
    __shared__ float pA[4][OBS];
    __shared__ float pC[2][HID];
    __shared__ float wq[4];

    const int b = blockIdx.x;
    const int t = threadIdx.x;
    const float* y = &Y[b * SL * OBS];

    for (int u = t; u < OBS * HID; u += 256) {
        const int a = u / HID, k = u % HID;
        sCt[k * OBS + a] = Cg[u];
    }
    for (int u = t; u < HID * HID; u += 256) {
        const int i = u / HID, k = u % HID;
        sAt[k * HID + i] = Ag[u];
    }
    if (t < HID) sx[t] = 0.f;
    __syncthreads();

    const int o  = t & 63;   // output for C-row / W phases
    const int sg = t >> 6;   // 0..3 (k-segment)
    const int L  = t & 127;  // output for x'-phase
    const int s2 = t >> 7;   // 0..1 (k-segment)
    const int ncv = *ncvp;
    float q = 0.f;

    for (int i = 0; i < SL; ++i) {
        const int s = (i < ncv) ? i : (ncv - 1);
        const float* Ws  = Wg   + s * OBS * OBS;
        const float* AKs = AKtg + s * OBS * HID;

        // phase 1: partials of C·x (4-way) and A·x (2-way)
        float a1 = 0.f;
        #pragma unroll 7
        for (int kk = 0; kk < 21; ++kk) {
            const int k = sg * 21 + kk;
            a1 += sCt[k * OBS + o] * sx[k];
        }
        pA[sg][o] = a1;
        float c1 = 0.f;
        if (L < HID) {
            #pragma unroll 6
            for (int kk = 0; kk < 42; ++kk) {
                const int k = s2 * 42 + kk;
                c1 += sAt[k * HID + L] * sx[k];
            }
        }
        __syncthreads();

        // phase 2: e = y - C·x
        if (t < OBS)
            se[t] = y[i * OBS + t] - (pA[0][t] + pA[1][t] + pA[2][t] + pA[3][t]);
        __syncthreads();

        // phase 3: q-partial (W sym: col o) + AK·e partial
        float w1 = 0.f;
        #pragma unroll 4
        for (int m = 0; m < 16; ++m) {
            const int k = sg * 16 + m;
            w1 += Ws[k * OBS + o] * se[k];
        }
        q += se[o] * w1;
        if (L < HID) {
            #pragma unroll 4
            for (int m = 0; m < 32; ++m) {
                const int mm = s2 * 32 + m;
                c1 += AKs[mm * HID + L] * se[mm];
            }
            pC[s2][L] = c1;
        }
        __syncthreads();

        // phase 4: x' commit
        if (t < HID) sx[t] = pC[0][t] + pC[1][t];
        __syncthreads();
    }

    #pragma unroll
    for (int m = 32; m >= 1; m >>= 1)
        q += __shfl_xor(q, m);
    if ((t & 63) == 0) wq[t >> 6] = q;
    __syncthreads();
    if (t == 0) partials[b] = wq[0] + wq[1] + wq[2] + wq[3];
}

// ---------------------------------------------------------------------------
__global__ void finalize_kernel(const float* __restrict__ partials,
                                float* __restrict__ out)
{
    const int t = threadIdx.x;
    float q = (t < BATCH) ? partials[t] : 0.0f;
    #pragma unroll
    for (int m = 32; m >= 1; m >>= 1)
        q += __shfl_xor(q, m);
    if (t == 0) out[0] = q * (1.0f / (float)(BATCH * SL * HID));
}

// ---------------------------------------------------------------------------
extern "C" void kernel_launch(void* const* d_in, const int* in_sizes, int n_in,
                              void* d_out, int out_size, void* d_ws, size_t ws_size,
                              hipStream_t stream)
{
    const float* Y = (const float*)d_in[0];   // (32, 3072) f32
    const float* A = (const float*)d_in[1];   // (84, 84)   f32
    const float* C = (const float*)d_in[2];   // (64, 84)   f32
    // d_in[3] = step (unused)

    float* ws = (float*)d_ws;
    float* AKtg = ws;                          // SL*OBS*HID = 258048
    float* Wg   = AKtg + SL * OBS * HID;       // SL*OBS*OBS = 196608
    float* partials = Wg + SL * OBS * OBS;     // 32
    int*   ncvp = (int*)(partials + BATCH);    // 1

    (void)hipFuncSetAttribute((const void*)riccati_kernel,
                              hipFuncAttributeMaxDynamicSharedMemorySize,
                              SMEM_BYTES);

    riccati_kernel<<<1, 512, SMEM_BYTES, stream>>>(A, C, AKtg, Wg, ncvp);
    sweep_kernel<<<BATCH, 256, 0, stream>>>(Y, A, C, AKtg, Wg, ncvp, partials);
    finalize_kernel<<<1, 64, 0, stream>>>(partials, (float*)d_out);
}

// Round 7
// 392.447 us; speedup vs baseline: 2.1219x; 1.3870x over previous
//
#include <hip/hip_runtime.h>

#define SL    48   // sequence length
#define OBS   64   // observation dim
#define HID   84   // hidden dim
#define BATCH 32
#define PTOL  5e-3f  // tol on max|dW|,|dAK| between consecutive Riccati steps

// Riccati LDS layout (floats); every OFF*4 is 16B-aligned.
#define OFF_P   0        // 84 x 96 swizzled (P, symmetric)
#define OFF_T2  8064     // 64 x 96 swizzled (T2 = C*P)
#define OFF_G1  14208    // 84 x 96 swizzled (G1 = A*P)
#define OFF_V   22272    // 84 x 64 swizzled (V = A*P*C^T)
#define OFF_S   27648    // 64 x 64 swizzled (S -> W in place)
#define OFF_AK  31744    // 84 x 64 swizzled (AK = V*W)
#define OFF_RB  37120    // 2 x (4 x 64) GJ pivot row panels (double buffer)
#define OFF_CB  37632    // 2 x (64 x 4) GJ pivot col panels (double buffer)
#define OFF_RED 38144    // 16
#define SMEM_F  38160
#define SMEM_BYTES (SMEM_F * 4)   // 152,640 B < 160 KiB

__device__ __forceinline__ int swz(int row, int c) { return c ^ ((row >> 2) & 7); }

// NT-GEMM 4x4 tile: acc[r][s] += sum_k X[i0+r][k] * Y[j0+s][k], k = 4*KC.
template<int KC, int XS, bool XSW, int YS, bool YSW>
__device__ __forceinline__ void tile_nt(const float* __restrict__ X,
                                        const float* __restrict__ Y,
                                        int i0, int j0, float acc[4][4])
{
    const int xk = XSW ? ((i0 >> 2) & 7) : 0;
    const int yk = YSW ? ((j0 >> 2) & 7) : 0;
    #pragma unroll 4
    for (int c = 0; c < KC; ++c) {
        const int xc = (XSW ? (c ^ xk) : c) << 2;
        const int yc = (YSW ? (c ^ yk) : c) << 2;
        float4 a[4], b[4];
        #pragma unroll
        for (int r = 0; r < 4; ++r)
            a[r] = *reinterpret_cast<const float4*>(&X[(i0 + r) * XS + xc]);
        #pragma unroll
        for (int s = 0; s < 4; ++s)
            b[s] = *reinterpret_cast<const float4*>(&Y[(j0 + s) * YS + yc]);
        #pragma unroll
        for (int r = 0; r < 4; ++r)
            #pragma unroll
            for (int s = 0; s < 4; ++s)
                acc[r][s] += a[r].x * b[s].x + a[r].y * b[s].y
                           + a[r].z * b[s].z + a[r].w * b[s].w;
    }
}

__device__ __forceinline__ void inv4_inplace(float a[4][4])
{
    float o[4][4] = {{1,0,0,0},{0,1,0,0},{0,0,1,0},{0,0,0,1}};
    #pragma unroll
    for (int p = 0; p < 4; ++p) {
        const float f = 1.0f / a[p][p];
        #pragma unroll
        for (int c = 0; c < 4; ++c) { a[p][c] *= f; o[p][c] *= f; }
        #pragma unroll
        for (int r = 0; r < 4; ++r) {
            if (r == p) continue;
            const float g = a[r][p];
            #pragma unroll
            for (int c = 0; c < 4; ++c) { a[r][c] -= g * a[p][c]; o[r][c] -= g * o[p][c]; }
        }
    }
    #pragma unroll
    for (int r = 0; r < 4; ++r)
        #pragma unroll
        for (int c = 0; c < 4; ++c) a[r][c] = o[r][c];
}

// ---------------------------------------------------------------------------
// Phase 1: Riccati sweep. Single block, 1024 threads (16 waves = 4/SIMD),
// all-LDS working set. Emits AK^T and W per step; early exit on convergence.
// ---------------------------------------------------------------------------
__global__ __launch_bounds__(1024)
void riccati_kernel(const float* __restrict__ Ag,   // HID x HID
                    const float* __restrict__ Cg,   // OBS x HID
                    float* __restrict__ AKtg,       // SL * OBS * HID
                    float* __restrict__ Wg,         // SL * OBS * OBS
                    int*   __restrict__ ncvp)
{
    extern __shared__ float smem[];
    float*  sP   = smem + OFF_P;
    float*  sT2  = smem + OFF_T2;
    float*  sG1  = smem + OFF_G1;
    float*  sV   = smem + OFF_V;
    float*  sS   = smem + OFF_S;
    float*  sAK  = smem + OFF_AK;
    float*  rbuf = smem + OFF_RB;   // [2][4*64]
    float*  cbuf = smem + OFF_CB;   // [2][64*4]
    float*  sRed = smem + OFF_RED;
    float4* sP4  = reinterpret_cast<float4*>(sP);
    float4* sT24 = reinterpret_cast<float4*>(sT2);
    float4* sG14 = reinterpret_cast<float4*>(sG1);
    float4* sV4  = reinterpret_cast<float4*>(sV);
    float4* sS4  = reinterpret_cast<float4*>(sS);
    float4* sAK4 = reinterpret_cast<float4*>(sAK);

    const int t = threadIdx.x;

    // P = I
    for (int u = t; u < HID * 24; u += 1024) {
        const int row = u / 24, pc = u % 24;
        const int lc = pc ^ ((row >> 2) & 7);
        float4 v = make_float4(0.f, 0.f, 0.f, 0.f);
        if (lc < 21) {
            const int base = lc * 4;
            if (row == base)     v.x = 1.f;
            if (row == base + 1) v.y = 1.f;
            if (row == base + 2) v.z = 1.f;
            if (row == base + 3) v.w = 1.f;
        }
        sP4[row * 24 + pc] = v;
    }
    __syncthreads();

    int ncv = SL;
    for (int step = 0; step < SL; ++step) {
        // ---- P1: T2 = C * P  (64 x 84)
        if (t < 336) {
            const int a0 = (t / 21) * 4, i0 = (t % 21) * 4;
            float acc[4][4] = {};
            tile_nt<21, HID, false, 96, true>(Cg, sP, a0, i0, acc);
            #pragma unroll
            for (int r = 0; r < 4; ++r)
                sT24[(a0 + r) * 24 + swz(a0 + r, i0 >> 2)] =
                    make_float4(acc[r][0], acc[r][1], acc[r][2], acc[r][3]);
        }
        __syncthreads();

        // ---- P2: S = T2*C^T (256 tiles), V = A*T2^T (336), G1 = A*P (441)
        //         also seed GJ group-0 pivot panels from S tiles
        for (int u = t; u < 1033; u += 1024) {
            if (u < 256) {
                const int a0 = (u / 16) * 4, b0 = (u % 16) * 4;
                float acc[4][4] = {};
                tile_nt<21, 96, true, HID, false>(sT2, Cg, a0, b0, acc);
                #pragma unroll
                for (int r = 0; r < 4; ++r)
                    sS4[(a0 + r) * 16 + swz(a0 + r, b0 >> 2)] =
                        make_float4(acc[r][0], acc[r][1], acc[r][2], acc[r][3]);
                if (a0 < 4) {
                    #pragma unroll
                    for (int r = 0; r < 4; ++r)
                        #pragma unroll
                        for (int s = 0; s < 4; ++s)
                            rbuf[(a0 + r) * 64 + b0 + s] = acc[r][s];
                }
                if (b0 == 0) {
                    #pragma unroll
                    for (int r = 0; r < 4; ++r)
                        #pragma unroll
                        for (int s = 0; s < 4; ++s)
                            cbuf[(a0 + r) * 4 + s] = acc[r][s];
                }
            } else if (u < 592) {
                const int v = u - 256;
                const int i0 = (v / 16) * 4, j0 = (v % 16) * 4;
                float acc[4][4] = {};
                tile_nt<21, HID, false, 96, true>(Ag, sT2, i0, j0, acc);
                #pragma unroll
                for (int r = 0; r < 4; ++r)
                    sV4[(i0 + r) * 16 + swz(i0 + r, j0 >> 2)] =
                        make_float4(acc[r][0], acc[r][1], acc[r][2], acc[r][3]);
            } else {
                const int w = u - 592;
                const int i0 = (w / 21) * 4, j0 = (w % 21) * 4;
                float acc[4][4] = {};
                tile_nt<21, HID, false, 96, true>(Ag, sP, i0, j0, acc);
                #pragma unroll
                for (int r = 0; r < 4; ++r)
                    sG14[(i0 + r) * 24 + swz(i0 + r, j0 >> 2)] =
                        make_float4(acc[r][0], acc[r][1], acc[r][2], acc[r][3]);
            }
        }
        __syncthreads();

        // ---- P3: block-4 Gauss-Jordan inverse of S (SPD), 1 barrier/group
        //          1024 threads: exactly one (row, chunk) cell per thread.
        for (int g = 0; g < 16; ++g) {
            const int p0 = g * 4;
            const float* rb  = rbuf + (g & 1) * 256;
            const float* cb  = cbuf + (g & 1) * 256;
            float* rbn = rbuf + ((g + 1) & 1) * 256;
            float* cbn = cbuf + ((g + 1) & 1) * 256;

            // replicated 4x4 pivot inverse
            float m[4][4];
            #pragma unroll
            for (int r = 0; r < 4; ++r)
                #pragma unroll
                for (int c = 0; c < 4; ++c) m[r][c] = rb[r * 64 + p0 + c];
            inv4_inplace(m);

            const int i = t >> 4, c = t & 15;
            const bool piv = (i >= p0) && (i < p0 + 4);
            float o[4];
            if (piv) {
                const int r = i - p0;
                if (c == g) {
                    o[0] = m[r][0]; o[1] = m[r][1]; o[2] = m[r][2]; o[3] = m[r][3];
                } else {
                    #pragma unroll
                    for (int jj = 0; jj < 4; ++jj) {
                        float s = 0.f;
                        #pragma unroll
                        for (int l = 0; l < 4; ++l) s += m[r][l] * rb[l * 64 + 4 * c + jj];
                        o[jj] = s;
                    }
                }
            } else {
                float e4[4];
                #pragma unroll
                for (int l = 0; l < 4; ++l) {
                    float s = 0.f;
                    #pragma unroll
                    for (int mm = 0; mm < 4; ++mm) s += cb[i * 4 + mm] * m[mm][l];
                    e4[l] = s;
                }
                if (c == g) {
                    o[0] = -e4[0]; o[1] = -e4[1]; o[2] = -e4[2]; o[3] = -e4[3];
                } else {
                    const float4 old = sS4[i * 16 + swz(i, c)];
                    o[0] = old.x; o[1] = old.y; o[2] = old.z; o[3] = old.w;
                    #pragma unroll
                    for (int l = 0; l < 4; ++l) {
                        const float el = e4[l];
                        #pragma unroll
                        for (int jj = 0; jj < 4; ++jj) o[jj] -= el * rb[l * 64 + 4 * c + jj];
                    }
                }
            }
            sS4[i * 16 + swz(i, c)] = make_float4(o[0], o[1], o[2], o[3]);
            if (g < 15) {
                if (i >= p0 + 4 && i < p0 + 8) {
                    #pragma unroll
                    for (int jj = 0; jj < 4; ++jj)
                        rbn[(i - p0 - 4) * 64 + 4 * c + jj] = o[jj];
                }
                if (c == g + 1) {
                    #pragma unroll
                    for (int jj = 0; jj < 4; ++jj) cbn[i * 4 + jj] = o[jj];
                }
            }
            __syncthreads();
        }

        // ---- P4: AK = V*W -> sAK + AKtg (transposed); stream W; convergence
        float maxd = 0.0f;
        float* AKtstep = AKtg + step * OBS * HID;
        const float* AKtprev = AKtg + (step - 1) * OBS * HID;
        if (t < 336) {
            const int i0 = (t / 16) * 4, j0 = (t % 16) * 4;
            float acc[4][4] = {};
            tile_nt<16, 64, true, 64, true>(sV, sS, i0, j0, acc);
            #pragma unroll
            for (int r = 0; r < 4; ++r)
                sAK4[(i0 + r) * 16 + swz(i0 + r, j0 >> 2)] =
                    make_float4(acc[r][0], acc[r][1], acc[r][2], acc[r][3]);
            #pragma unroll
            for (int s = 0; s < 4; ++s) {
                const float4 nv = make_float4(acc[0][s], acc[1][s], acc[2][s], acc[3][s]);
                if (step > 0) {
                    const float4 ov =
                        *reinterpret_cast<const float4*>(&AKtprev[(j0 + s) * HID + i0]);
                    maxd = fmaxf(maxd, fmaxf(fmaxf(fabsf(nv.x - ov.x), fabsf(nv.y - ov.y)),
                                             fmaxf(fabsf(nv.z - ov.z), fabsf(nv.w - ov.w))));
                }
                *reinterpret_cast<float4*>(&AKtstep[(j0 + s) * HID + i0]) = nv;
            }
        }
        {
            float* Wstep = Wg + step * OBS * OBS;
            const float* Wprev = Wg + (step - 1) * OBS * OBS;
            const int row = t >> 4, c = t & 15;
            const float4 nv = sS4[row * 16 + swz(row, c)];
            if (step > 0) {
                const float4 ov = reinterpret_cast<const float4*>(Wprev)[row * 16 + c];
                maxd = fmaxf(maxd, fmaxf(fmaxf(fabsf(nv.x - ov.x), fabsf(nv.y - ov.y)),
                                         fmaxf(fabsf(nv.z - ov.z), fabsf(nv.w - ov.w))));
            }
            reinterpret_cast<float4*>(Wstep)[row * 16 + c] = nv;
        }
        #pragma unroll
        for (int mo = 32; mo >= 1; mo >>= 1)
            maxd = fmaxf(maxd, __shfl_xor(maxd, mo));
        if ((t & 63) == 0) sRed[t >> 6] = maxd;
        __syncthreads();
        float mm = sRed[0];
        #pragma unroll
        for (int w = 1; w < 16; ++w) mm = fmaxf(mm, sRed[w]);
        if (step > 0 && mm < PTOL) { ncv = step + 1; break; }
        if (step == SL - 1) break;

        // ---- P5: P' = G1*A^T - AK*V^T + I
        if (t < 441) {
            const int i0 = (t / 21) * 4, j0 = (t % 21) * 4;
            float a1[4][4] = {}, a2[4][4] = {};
            tile_nt<21, 96, true, HID, false>(sG1, Ag, i0, j0, a1);
            tile_nt<16, 64, true, 64, true>(sAK, sV, i0, j0, a2);
            #pragma unroll
            for (int r = 0; r < 4; ++r) {
                float4 v = make_float4(a1[r][0] - a2[r][0], a1[r][1] - a2[r][1],
                                       a1[r][2] - a2[r][2], a1[r][3] - a2[r][3]);
                if (i0 + r == j0 + 0) v.x += 1.f;
                if (i0 + r == j0 + 1) v.y += 1.f;
                if (i0 + r == j0 + 2) v.z += 1.f;
                if (i0 + r == j0 + 3) v.w += 1.f;
                sP4[(i0 + r) * 24 + swz(i0 + r, j0 >> 2)] = v;
            }
        }
        __syncthreads();
    }

    if (t == 0) *ncvp = ncv;
}

// ---------------------------------------------------------------------------
// Phase 2: per-batch Kalman sweep. 256 threads (4 waves), split-K GEMVs.
// Converged W / AK staged in LDS (used for all steps i >= ncv-1).
// Sweep LDS layout (floats):
#define SW_CT   0        // 84 x 64  C^T
#define SW_AT   5376     // 84 x 84  A^T
#define SW_WC   12432    // 64 x 64  converged W
#define SW_AKC  16528    // 64 x 84  converged AK^T
#define SW_X    21904    // 88 (84 padded)
#define SW_E    21992    // 64
#define SW_PA   22056    // 4 x 64
#define SW_PC   22312    // 2 x 84
#define SW_WQ   22480    // 4
#define SW_F    22484
#define SW_BYTES (SW_F * 4)      // 89,936 B
// ---------------------------------------------------------------------------
__global__ __launch_bounds__(256)
void sweep_kernel(const float* __restrict__ Y,     // BATCH x (SL*OBS)
                  const float* __restrict__ Ag,
                  const float* __restrict__ Cg,
                  const float* __restrict__ AKtg,  // SL * OBS * HID
                  const float* __restrict__ Wg,    // SL * OBS * OBS
                  const int*   __restrict__ ncvp,
                  float* __restrict__ partials)
{
    extern __shared__ float sm[];
    float* sCt  = sm + SW_CT;   // [k][o] = C[o][k]
    float* sAt  = sm + SW_AT;   // [k][i] = A[i][k]
    float* sWc  = sm + SW_WC;
    float* sAKc = sm + SW_AKC;
    float* sx   = sm + SW_X;
    float* se   = sm + SW_E;
    float* pA   = sm + SW_PA;
    float* pC   = sm + SW_PC;
    float* wq   = sm + SW_WQ;

    const int b = blockIdx.x;
    const int t = threadIdx.x;
    const float* y = &Y[b * SL * OBS];
    const int ncv = *ncvp;

    for (int u = t; u < OBS * HID; u += 256) {
        const int a = u / HID, k = u % HID;
        sCt[k * OBS + a] = Cg[u];
    }
    for (int u = t; u < HID * HID; u += 256) {
        const int i = u / HID, k = u % HID;
        sAt[k * HID + i] = Ag[u];
    }
    {
        const float4* Wc  = reinterpret_cast<const float4*>(Wg   + (ncv - 1) * OBS * OBS);
        const float4* AKc = reinterpret_cast<const float4*>(AKtg + (ncv - 1) * OBS * HID);
        for (int u = t; u < (OBS * OBS) / 4; u += 256)
            reinterpret_cast<float4*>(sWc)[u] = Wc[u];
        for (int u = t; u < (OBS * HID) / 4; u += 256)
            reinterpret_cast<float4*>(sAKc)[u] = AKc[u];
    }
    if (t < HID) sx[t] = 0.f;
    __syncthreads();

    const int o  = t & 63;   // output for C-row / W phases
    const int sg = t >> 6;   // 0..3 (k-segment)
    const int L  = t & 127;  // output for x'-phase
    const int s2 = t >> 7;   // 0..1 (k-segment)
    float q = 0.f;

    for (int i = 0; i < SL; ++i) {
        const bool cvg = (i >= ncv - 1);
        const float* Ws  = Wg   + i * OBS * OBS;
        const float* AKs = AKtg + i * OBS * HID;

        // phase 1: partials of C·x (4-way) and A·x (2-way)
        float a1 = 0.f;
        #pragma unroll 7
        for (int kk = 0; kk < 21; ++kk) {
            const int k = sg * 21 + kk;
            a1 += sCt[k * OBS + o] * sx[k];
        }
        pA[sg * OBS + o] = a1;
        float c1 = 0.f;
        if (L < HID) {
            #pragma unroll 6
            for (int kk = 0; kk < 42; ++kk) {
                const int k = s2 * 42 + kk;
                c1 += sAt[k * HID + L] * sx[k];
            }
        }
        __syncthreads();

        // phase 2: e = y - C·x
        if (t < OBS)
            se[t] = y[i * OBS + t]
                  - (pA[t] + pA[OBS + t] + pA[2 * OBS + t] + pA[3 * OBS + t]);
        __syncthreads();

        // phase 3: q-partial (W sym: col o) + AK·e partial
        float w1 = 0.f;
        if (cvg) {
            #pragma unroll 4
            for (int m = 0; m < 16; ++m) {
                const int k = sg * 16 + m;
                w1 += sWc[k * OBS + o] * se[k];
            }
        } else {
            #pragma unroll 4
            for (int m = 0; m < 16; ++m) {
                const int k = sg * 16 + m;
                w1 += Ws[k * OBS + o] * se[k];
            }
        }
        q += se[o] * w1;
        if (L < HID) {
            if (cvg) {
                #pragma unroll 4
                for (int m = 0; m < 32; ++m) {
                    const int mm = s2 * 32 + m;
                    c1 += sAKc[mm * HID + L] * se[mm];
                }
            } else {
                #pragma unroll 4
                for (int m = 0; m < 32; ++m) {
                    const int mm = s2 * 32 + m;
                    c1 += AKs[mm * HID + L] * se[mm];
                }
            }
            pC[s2 * HID + L] = c1;
        }
        __syncthreads();

        // phase 4: x' commit
        if (t < HID) sx[t] = pC[t] + pC[HID + t];
        __syncthreads();
    }

    #pragma unroll
    for (int m = 32; m >= 1; m >>= 1)
        q += __shfl_xor(q, m);
    if ((t & 63) == 0) wq[t >> 6] = q;
    __syncthreads();
    if (t == 0) partials[b] = wq[0] + wq[1] + wq[2] + wq[3];
}

// ---------------------------------------------------------------------------
__global__ void finalize_kernel(const float* __restrict__ partials,
                                float* __restrict__ out)
{
    const int t = threadIdx.x;
    float q = (t < BATCH) ? partials[t] : 0.0f;
    #pragma unroll
    for (int m = 32; m >= 1; m >>= 1)
        q += __shfl_xor(q, m);
    if (t == 0) out[0] = q * (1.0f / (float)(BATCH * SL * HID));
}

// ---------------------------------------------------------------------------
extern "C" void kernel_launch(void* const* d_in, const int* in_sizes, int n_in,
                              void* d_out, int out_size, void* d_ws, size_t ws_size,
                              hipStream_t stream)
{
    const float* Y = (const float*)d_in[0];   // (32, 3072) f32
    const float* A = (const float*)d_in[1];   // (84, 84)   f32
    const float* C = (const float*)d_in[2];   // (64, 84)   f32
    // d_in[3] = step (unused)

    float* ws = (float*)d_ws;
    float* AKtg = ws;                          // SL*OBS*HID = 258048
    float* Wg   = AKtg + SL * OBS * HID;       // SL*OBS*OBS = 196608
    float* partials = Wg + SL * OBS * OBS;     // 32
    int*   ncvp = (int*)(partials + BATCH);    // 1

    (void)hipFuncSetAttribute((const void*)riccati_kernel,
                              hipFuncAttributeMaxDynamicSharedMemorySize,
                              SMEM_BYTES);
    (void)hipFuncSetAttribute((const void*)sweep_kernel,
                              hipFuncAttributeMaxDynamicSharedMemorySize,
                              SW_BYTES);

    riccati_kernel<<<1, 1024, SMEM_BYTES, stream>>>(A, C, AKtg, Wg, ncvp);
    sweep_kernel<<<BATCH, 256, SW_BYTES, stream>>>(Y, A, C, AKtg, Wg, ncvp, partials);
    finalize_kernel<<<1, 64, 0, stream>>>(partials, (float*)d_out);
}